// Round 14
// baseline (438.531 us; speedup 1.0000x reference)
//
#include <hip/hip_runtime.h>
#include <hip/hip_bf16.h>

// GPT3 attention block, B=2 S=2048 D=2048 H=16 Dh=128.
// 4-phase/iter 128x128 counted-vmcnt GEMM (2 blocks/CU, L2/L3-aware XCD
// map) + persistent-block (atomic LPT) swapped-QK^T 32x32 flash attention.

typedef __bf16 bf16x8 __attribute__((ext_vector_type(8)));
typedef float f32x4 __attribute__((ext_vector_type(4)));
typedef float f32x16 __attribute__((ext_vector_type(16)));
typedef unsigned short u16;
typedef unsigned int u32;

#define DEV static __device__ __forceinline__

DEV void gload_lds16(const void* g, void* l) {
  __builtin_amdgcn_global_load_lds(
      (const __attribute__((address_space(1))) void*)g,
      (__attribute__((address_space(3))) void*)l, 16, 0, 0);
}

DEV f32x4 mfma16(bf16x8 a, bf16x8 b, f32x4 c) {
  return __builtin_amdgcn_mfma_f32_16x16x32_bf16(a, b, c, 0, 0, 0);
}

DEV f32x16 mfma32(bf16x8 a, bf16x8 b, f32x16 c) {
  return __builtin_amdgcn_mfma_f32_32x32x16_bf16(a, b, c, 0, 0, 0);
}

DEV u16 f2bf(float x) {
  return __builtin_bit_cast(u16, __float2bfloat16(x));
}

DEV u32 pack2(float lo, float hi_) {
  return (u32)f2bf(lo) | ((u32)f2bf(hi_) << 16);
}

#define BAR() __builtin_amdgcn_s_barrier()

// ---------------- fp32 -> bf16 conversion ----------------------------
__global__ void __launch_bounds__(256) conv_f32_bf16(
    const float* __restrict__ in, u16* __restrict__ out) {
  const size_t i = ((size_t)blockIdx.x * 256 + threadIdx.x) * 4;
  const float4 v = *reinterpret_cast<const float4*>(in + i);
  ushort4 o;
  o.x = f2bf(v.x); o.y = f2bf(v.y); o.z = f2bf(v.z); o.w = f2bf(v.w);
  *reinterpret_cast<ushort4*>(out + i) = o;
}

__global__ void __launch_bounds__(256) conv_all(
    const float* __restrict__ s0, const float* __restrict__ s1,
    const float* __restrict__ s2, const float* __restrict__ s3,
    const float* __restrict__ s4, const float* __restrict__ s5,
    const float* __restrict__ s6,
    u16* __restrict__ d0, u16* __restrict__ d1, u16* __restrict__ d2,
    u16* __restrict__ d3, u16* __restrict__ d4, u16* __restrict__ d5,
    u16* __restrict__ d6, const size_t nact, const size_t nw) {
  const int j = blockIdx.y;
  const size_t i = ((size_t)blockIdx.x * 256 + threadIdx.x) * 4;
  const float* s; u16* d; size_t n;
  switch (j) {
    case 0: s = s0; d = d0; n = nact; break;
    case 1: s = s1; d = d1; n = nact; break;
    case 2: s = s2; d = d2; n = nact; break;
    case 3: s = s3; d = d3; n = nw; break;
    case 4: s = s4; d = d4; n = nw; break;
    case 5: s = s5; d = d5; n = nw; break;
    default: s = s6; d = d6; n = nw; break;
  }
  if (i >= n) return;
  const float4 v = *reinterpret_cast<const float4*>(s + i);
  ushort4 o;
  o.x = f2bf(v.x); o.y = f2bf(v.y); o.z = f2bf(v.z); o.w = f2bf(v.w);
  *reinterpret_cast<ushort4*>(d + i) = o;
}

// ---------------- 4-phase 128x128 GEMM: C = A @ B^T + bias ------------
// (unchanged from r13: 16 MFMA/phase, counted vmcnt(4) at ph1/ph3,
// pair-row XOR swizzle, 2 blocks/CU)
#define GK 2048

DEV void gemm128_core(const u16* __restrict__ A, const u16* __restrict__ Bw,
                      const float* __restrict__ bias, void* __restrict__ Cout,
                      const int m0, const int n0, const int N,
                      const int out_f32, u16* AsB, u16* BsB) {
  const int tid = threadIdx.x;
  const int lane = tid & 63;
  const int wid = tid >> 6;
  const int wr = wid >> 1, wc = wid & 1;
  const int g = lane >> 4;
  const int r16 = lane & 15;

  int offA[2], offB[2], dstE[2];
#pragma unroll
  for (int rr = 0; rr < 2; ++rr) {
    const int G = rr * 256 + tid;
    const int rp = G >> 3;
    const int s = (G & 7) ^ (rp & 7);
    const int row = rp * 2 + (s >> 2);
    const int ch = s & 3;
    offA[rr] = (m0 + row) * GK + ch * 8;
    offB[rr] = (n0 + row) * GK + ch * 8;
    dstE[rr] = rr * 2048 + wid * 512;
  }

#define STAGE_A(kt, kh) do {                                              \
    u16* base_ = AsB + (((kt) & 1) * 2 + (kh)) * 4096;                    \
    const int go_ = (kt) * 64 + (kh) * 32;                                \
    gload_lds16(A + (size_t)(offA[0] + go_), base_ + dstE[0]);            \
    gload_lds16(A + (size_t)(offA[1] + go_), base_ + dstE[1]);            \
  } while (0)
#define STAGE_B(kt, kh) do {                                              \
    u16* base_ = BsB + (((kt) & 1) * 2 + (kh)) * 4096;                    \
    const int go_ = (kt) * 64 + (kh) * 32;                                \
    gload_lds16(Bw + (size_t)(offB[0] + go_), base_ + dstE[0]);           \
    gload_lds16(Bw + (size_t)(offB[1] + go_), base_ + dstE[1]);           \
  } while (0)
#define READ_A2(MH, buf) do {                                             \
    _Pragma("unroll") for (int i_ = 0; i_ < 2; ++i_) {                    \
      const int row_ = wr * 64 + ((MH) * 2 + i_) * 16 + r16;              \
      const int rp_ = row_ >> 1;                                          \
      const int sl_ = (((row_ & 1) << 2) | g) ^ (rp_ & 7);                \
      const int off_ = rp_ * 64 + sl_ * 8;                                \
      af[i_][0] = *(const bf16x8*)(AsB + ((buf) * 2 + 0) * 4096 + off_);  \
      af[i_][1] = *(const bf16x8*)(AsB + ((buf) * 2 + 1) * 4096 + off_);  \
    } } while (0)
#define READ_B4(buf) do {                                                 \
    _Pragma("unroll") for (int j_ = 0; j_ < 4; ++j_) {                    \
      const int row_ = wc * 64 + j_ * 16 + r16;                           \
      const int rp_ = row_ >> 1;                                          \
      const int sl_ = (((row_ & 1) << 2) | g) ^ (rp_ & 7);                \
      const int off_ = rp_ * 64 + sl_ * 8;                                \
      bf[j_][0] = *(const bf16x8*)(BsB + ((buf) * 2 + 0) * 4096 + off_);  \
      bf[j_][1] = *(const bf16x8*)(BsB + ((buf) * 2 + 1) * 4096 + off_);  \
    } } while (0)
#define MFMA16(MH) do {                                                   \
    __builtin_amdgcn_s_setprio(1);                                        \
    _Pragma("unroll") for (int i_ = 0; i_ < 2; ++i_)                      \
    _Pragma("unroll") for (int j_ = 0; j_ < 4; ++j_) {                    \
      f32x4 c_ = acc[(MH) * 2 + i_][j_];                                  \
      c_ = mfma16(af[i_][0], bf[j_][0], c_);                              \
      c_ = mfma16(af[i_][1], bf[j_][1], c_);                              \
      acc[(MH) * 2 + i_][j_] = c_;                                        \
    }                                                                     \
    __builtin_amdgcn_s_setprio(0);                                        \
  } while (0)

  f32x4 acc[4][4];
#pragma unroll
  for (int i = 0; i < 4; ++i)
#pragma unroll
    for (int j = 0; j < 4; ++j) acc[i][j] = {0.f, 0.f, 0.f, 0.f};

  bf16x8 af[2][2], bf[4][2];

  STAGE_B(0, 0); STAGE_B(0, 1); STAGE_A(0, 0); STAGE_A(0, 1);
  STAGE_B(1, 0); STAGE_B(1, 1);
  asm volatile("s_waitcnt vmcnt(4)" ::: "memory");
  BAR();

  for (int it = 0; it < 16; ++it) {
    const bool tail = (it == 15);
    const int T = 2 * it;
    const int b0 = T & 1, b1 = (T + 1) & 1;
    // ph0: tile T
    READ_A2(0, b0); READ_B4(b0);
    STAGE_A(T + 1, 0); STAGE_A(T + 1, 1);
    BAR(); MFMA16(0); BAR();
    // ph1
    READ_A2(1, b0);
    if (!tail) {
      STAGE_B(T + 2, 0); STAGE_B(T + 2, 1);
      asm volatile("s_waitcnt vmcnt(4)" ::: "memory");
    } else {
      asm volatile("s_waitcnt vmcnt(0)" ::: "memory");
    }
    BAR(); MFMA16(1); BAR();
    // ph2: tile T+1
    READ_A2(0, b1); READ_B4(b1);
    if (!tail) { STAGE_A(T + 2, 0); STAGE_A(T + 2, 1); }
    BAR(); MFMA16(0); BAR();
    // ph3
    READ_A2(1, b1);
    if (!tail) {
      STAGE_B(T + 3, 0); STAGE_B(T + 3, 1);
      asm volatile("s_waitcnt vmcnt(4)" ::: "memory");
    } else {
      asm volatile("s_waitcnt vmcnt(0)" ::: "memory");
    }
    BAR(); MFMA16(1); BAR();
  }

  const int rbase = m0 + wr * 64 + g * 4;
  const int cb = n0 + wc * 64 + r16;
#pragma unroll
  for (int i = 0; i < 4; ++i) {
#pragma unroll
    for (int j = 0; j < 4; ++j) {
      const int c = cb + j * 16;
      const float bv = bias[c];
#pragma unroll
      for (int r = 0; r < 4; ++r) {
        const float v = acc[i][j][r] + bv;
        const size_t idx = (size_t)(rbase + i * 16 + r) * N + c;
        if (out_f32) ((float*)Cout)[idx] = v;
        else ((u16*)Cout)[idx] = f2bf(v);
      }
    }
  }
#undef STAGE_A
#undef STAGE_B
#undef READ_A2
#undef READ_B4
#undef MFMA16
}

__global__ void __launch_bounds__(256, 2) gemm_qkv3(
    const u16* __restrict__ A0, const u16* __restrict__ A1,
    const u16* __restrict__ A2, const u16* __restrict__ W0,
    const u16* __restrict__ W1, const u16* __restrict__ W2,
    const float* __restrict__ b0, const float* __restrict__ b1,
    const float* __restrict__ b2, u16* __restrict__ C0,
    u16* __restrict__ C1, u16* __restrict__ C2) {
  __shared__ u16 AsB[4 * 4096];
  __shared__ u16 BsB[4 * 4096];
  const int xcd = blockIdx.x & 7;
  const int t = blockIdx.x >> 3;
  const int which = t >> 6;
  const int r = t & 63;
  const int m0 = (xcd * 4 + (r >> 4)) << 7;
  const int n0 = (r & 15) << 7;
  const u16* A = which == 0 ? A0 : which == 1 ? A1 : A2;
  const u16* W = which == 0 ? W0 : which == 1 ? W1 : W2;
  const float* bb = which == 0 ? b0 : which == 1 ? b1 : b2;
  u16* C = which == 0 ? C0 : which == 1 ? C1 : C2;
  gemm128_core(A, W, bb, C, m0, n0, 2048, 0, AsB, BsB);
}

__global__ void __launch_bounds__(256, 2) gemm_one(
    const u16* __restrict__ A, const u16* __restrict__ Bw,
    const float* __restrict__ bias, void* __restrict__ Cout,
    const int out_f32) {
  __shared__ u16 AsB[4 * 4096];
  __shared__ u16 BsB[4 * 4096];
  const int xcd = blockIdx.x & 7;
  const int t = blockIdx.x >> 3;
  const int m0 = (xcd * 4 + (t >> 4)) << 7;
  const int n0 = (t & 15) << 7;
  gemm128_core(A, Bw, bias, Cout, m0, n0, 2048, out_f32, AsB, BsB);
}

// ---------------- causal flash attention (persistent LPT blocks) ------
// r14: 768 persistent blocks (3/CU; LDS 48KB), atomic job counter over
// 512 (b,h,qt) segments ordered qt-DESCENDING (LPT): longest jobs start
// first, short jobs backfill. Fixes r13's 12.7% occupancy (static 2/CU
// pairing balanced totals but makespan = max of concurrent blocks).
#define SEQ 2048
#define DMODEL 2048
#define DH 128
#define QBLK 128
#define KBLK 64
#define NJOBS 512
#define C1 0.12751744f   // (1/sqrt(128)) * log2(e)
#define THR_RAW 62.73f   // defer-max threshold: 8 / C1

__global__ void __launch_bounds__(256, 3) flash_attn(
    const u16* __restrict__ Qh, const u16* __restrict__ Kh,
    const u16* __restrict__ Vh, u16* __restrict__ O,
    u32* __restrict__ ctr) {
  __shared__ u16 Ks[2][KBLK * DH];  // 32 KB
  __shared__ u16 Vt[DH * KBLK];     // 16 KB
  __shared__ int s_job;

  const int tid = threadIdx.x;
  const int lane = tid & 63;
  const int w = tid >> 6;
  const int hi = lane >> 5;
  const int l31 = lane & 31;

  const int krl = w * 16 + (lane >> 4);
  const int kg4 = w * 4 + (lane >> 4);
  const int du = lane & 15;

  for (;;) {
    if (tid == 0) s_job = (int)atomicAdd(ctr, 1u);
    __syncthreads();
    const int job = s_job;
    if (job >= NJOBS) return;

    // LPT order: qt descending with job index
    const int qt = 15 - (job >> 5);
    const int bh = job & 31;
    const int h = bh & 15;
    const int b = bh >> 4;
    const int q0 = qt * QBLK;
    const size_t rowbase = (size_t)b * SEQ;
    const int hoff = h * DH;
    const int qw = q0 + w * 32;
    const int qlane = qw + l31;

    bf16x8 aq[8];
    {
      const u16* qp = &Qh[(rowbase + qlane) * DMODEL + hoff + hi * 8];
#pragma unroll
      for (int c = 0; c < 8; ++c)
        aq[c] = *reinterpret_cast<const bf16x8*>(qp + c * 16);
    }

    f32x16 oacc[4];
#pragma unroll
    for (int dt = 0; dt < 4; ++dt)
#pragma unroll
      for (int r = 0; r < 16; ++r) oacc[dt][r] = 0.f;
    float mrow = -1e30f, lrow = 0.f;

    const int nkt = 2 * qt + 2;
    const int ktd = qw >> 6;

    auto stageK = [&](int kt) {
#pragma unroll
      for (int i = 0; i < 4; ++i) {
        const int r = krl + i * 4;
        const int cg = (lane & 15) ^ (r & 15);
        gload_lds16(&Kh[(rowbase + kt * KBLK + r) * DMODEL + hoff + cg * 8],
                    &Ks[kt & 1][(w * 16 + i * 4) * DH]);
      }
    };

    stageK(0);
    uint4 vv[4];
#pragma unroll
    for (int r = 0; r < 4; ++r)
      vv[r] = *reinterpret_cast<const uint4*>(
          &Vh[(rowbase + kg4 * 4 + r) * DMODEL + hoff + du * 8]);

    for (int kt = 0; kt < nkt; ++kt) {
      const int k0 = kt * KBLK;
      if (kt + 1 < nkt) {
        stageK(kt + 1);
        // oldest retired first (incl. prev job's stores): K(kt)+vv landed,
        // K(kt+1)'s 4 loads stay in flight.
        asm volatile("s_waitcnt vmcnt(4)" ::: "memory");
      } else {
        asm volatile("s_waitcnt vmcnt(0)" ::: "memory");
      }

#pragma unroll
      for (int j = 0; j < 8; ++j) {
        const int d = du * 8 + j;
        ushort4 pk4;
        pk4.x = ((const u16*)&vv[0])[j];
        pk4.y = ((const u16*)&vv[1])[j];
        pk4.z = ((const u16*)&vv[2])[j];
        pk4.w = ((const u16*)&vv[3])[j];
        const int slot = (((kg4 >> 1) ^ ((d >> 2) & 7)) * 8) + (kg4 & 1) * 4;
        *reinterpret_cast<ushort4*>(&Vt[d * KBLK + slot]) = pk4;
      }
      asm volatile("s_waitcnt lgkmcnt(0)" ::: "memory");
      BAR();

      const bool active = (kt <= ktd);
      const u16* kb = &Ks[kt & 1][0];
      float p[2][16];
      bool act1 = false;

      if (active) {
        const bool diag = (kt == ktd);
        act1 = (kt < ktd) || (w & 1);
        const bool m0q = diag && !(w & 1);
        const bool m1q = diag && (w & 1);
        {
          f32x16 s;
#pragma unroll
          for (int r = 0; r < 16; ++r) s[r] = 0.f;
          __builtin_amdgcn_s_setprio(1);
#pragma unroll
          for (int c = 0; c < 8; ++c) {
            const int row = l31;
            const bf16x8 kf = *reinterpret_cast<const bf16x8*>(
                &kb[row * DH + (((c * 2 + hi) ^ (row & 15)) * 8)]);
            s = mfma32(kf, aq[c], s);
          }
          __builtin_amdgcn_s_setprio(0);
#pragma unroll
          for (int r = 0; r < 16; ++r) {
            const int krow = (r & 3) + 8 * (r >> 2) + 4 * hi;
            p[0][r] = (m0q && (k0 + krow > qlane)) ? -1e9f : s[r];
          }
        }
        if (act1) {
          f32x16 s;
#pragma unroll
          for (int r = 0; r < 16; ++r) s[r] = 0.f;
          __builtin_amdgcn_s_setprio(1);
#pragma unroll
          for (int c = 0; c < 8; ++c) {
            const int row = 32 + l31;
            const bf16x8 kf = *reinterpret_cast<const bf16x8*>(
                &kb[row * DH + (((c * 2 + hi) ^ (row & 15)) * 8)]);
            s = mfma32(kf, aq[c], s);
          }
          __builtin_amdgcn_s_setprio(0);
#pragma unroll
          for (int r = 0; r < 16; ++r) {
            const int krow = (r & 3) + 8 * (r >> 2) + 4 * hi;
            p[1][r] = (m1q && (k0 + 32 + krow > qlane)) ? -1e9f : s[r];
          }
        } else {
#pragma unroll
          for (int r = 0; r < 16; ++r) p[1][r] = -1e9f;
        }
      }

      if (kt + 1 < nkt) {
#pragma unroll
        for (int r = 0; r < 4; ++r)
          vv[r] = *reinterpret_cast<const uint4*>(
              &Vh[(rowbase + k0 + KBLK + kg4 * 4 + r) * DMODEL + hoff +
                  du * 8]);
      }

      if (active) {
        float mx0 = fmaxf(p[0][0], p[1][0]);
        float mx1 = fmaxf(p[0][1], p[1][1]);
        float mx2 = fmaxf(p[0][2], p[1][2]);
        float mx3 = fmaxf(p[0][3], p[1][3]);
#pragma unroll
        for (int r = 4; r < 16; r += 4) {
          mx0 = fmaxf(mx0, fmaxf(p[0][r + 0], p[1][r + 0]));
          mx1 = fmaxf(mx1, fmaxf(p[0][r + 1], p[1][r + 1]));
          mx2 = fmaxf(mx2, fmaxf(p[0][r + 2], p[1][r + 2]));
          mx3 = fmaxf(mx3, fmaxf(p[0][r + 3], p[1][r + 3]));
        }
        float mx = fmaxf(fmaxf(mx0, mx1), fmaxf(mx2, mx3));
        mx = fmaxf(mx, __shfl_xor(mx, 32));

        const bool need = (mx > mrow + THR_RAW);
        if (__any((int)need)) {
          const float mn = fmaxf(mrow, mx);
          const float al = exp2f((mrow - mn) * C1);
          mrow = mn;
          lrow *= al;
#pragma unroll
          for (int r = 0; r < 16; ++r) {
            const float ar = __shfl(al, (r & 3) + 8 * (r >> 2) + 4 * hi);
#pragma unroll
            for (int dt = 0; dt < 4; ++dt) oacc[dt][r] *= ar;
          }
        }

        float s0 = 0.f, s1 = 0.f, s2 = 0.f, s3 = 0.f;
#pragma unroll
        for (int t = 0; t < 2; ++t)
#pragma unroll
          for (int r = 0; r < 16; r += 4) {
            p[t][r + 0] = exp2f((p[t][r + 0] - mrow) * C1);
            p[t][r + 1] = exp2f((p[t][r + 1] - mrow) * C1);
            p[t][r + 2] = exp2f((p[t][r + 2] - mrow) * C1);
            p[t][r + 3] = exp2f((p[t][r + 3] - mrow) * C1);
            s0 += p[t][r + 0]; s1 += p[t][r + 1];
            s2 += p[t][r + 2]; s3 += p[t][r + 3];
          }
        float sum = (s0 + s1) + (s2 + s3);
        sum += __shfl_xor(sum, 32);
        lrow += sum;

        u32 pk[2][8];
#pragma unroll
        for (int t = 0; t < 2; ++t)
#pragma unroll
          for (int m = 0; m < 8; ++m)
            pk[t][m] = pack2(p[t][2 * m], p[t][2 * m + 1]);

        __builtin_amdgcn_s_setprio(1);
#pragma unroll
        for (int ks = 0; ks < 4; ++ks) {
          if (ks >= 2 && !act1) break;
          const int t = ks >> 1;
          const int bs = (ks & 1) * 4;
          const u32 q0s = __shfl_xor(pk[t][bs + 0], 32);
          const u32 q1s = __shfl_xor(pk[t][bs + 1], 32);
          const u32 q2s = __shfl_xor(pk[t][bs + 2], 32);
          const u32 q3s = __shfl_xor(pk[t][bs + 3], 32);
          union { u32 u[4]; bf16x8 v; } pa;
          pa.u[0] = hi ? q2s : pk[t][bs + 0];
          pa.u[1] = hi ? q3s : pk[t][bs + 1];
          pa.u[2] = hi ? pk[t][bs + 2] : q0s;
          pa.u[3] = hi ? pk[t][bs + 3] : q1s;
#pragma unroll
          for (int dt = 0; dt < 4; ++dt) {
            const int d = dt * 32 + l31;
            const bf16x8 vf = *reinterpret_cast<const bf16x8*>(
                &Vt[d * KBLK + (((ks * 2 + hi) ^ ((d >> 2) & 7)) * 8)]);
            oacc[dt] = mfma32(pa.v, vf, oacc[dt]);
          }
        }
        __builtin_amdgcn_s_setprio(0);
      }

      BAR();
    }

    const float li = __builtin_amdgcn_rcpf(lrow);
#pragma unroll
    for (int r = 0; r < 16; ++r) {
      const int rowq = (r & 3) + 8 * (r >> 2) + 4 * hi;
      const float lr = __shfl(li, rowq);
      u16* op = &O[(rowbase + qw + rowq) * DMODEL + hoff + l31];
#pragma unroll
      for (int dt = 0; dt < 4; ++dt) op[dt * 32] = f2bf(oacc[dt][r] * lr);
    }
  }
}

// ---------------- launcher --------------------------------------------
extern "C" void kernel_launch(void* const* d_in, const int* in_sizes, int n_in,
                              void* d_out, int out_size, void* d_ws,
                              size_t ws_size, hipStream_t stream) {
  const int Bv = 2, S = 2048, D = 2048;
  const int M = Bv * S;
  const size_t NT = (size_t)M * D;   // 8388608
  const size_t NW = (size_t)D * D;   // 4194304

  const float* q = (const float*)d_in[0];
  const float* k = (const float*)d_in[1];
  const float* v = (const float*)d_in[2];
  const float* wq_w = (const float*)d_in[4];
  const float* wq_b = (const float*)d_in[5];
  const float* wk_w = (const float*)d_in[6];
  const float* wk_b = (const float*)d_in[7];
  const float* wv_w = (const float*)d_in[8];
  const float* wv_b = (const float*)d_in[9];
  const float* dw = (const float*)d_in[10];
  const float* db = (const float*)d_in[11];
  float* out = (float*)d_out;

  const dim3 blk(256);
  const dim3 gattn(768);
  const size_t need = (7 * NT + 4 * NW) * 2 + 64;  // ~151 MB + ctr

  if (ws_size >= need) {
    u16* base = (u16*)d_ws;
    u16* Xq = base;
    u16* Xk = Xq + NT;
    u16* Xv = Xk + NT;
    u16* Wq = Xv + NT;
    u16* Wk = Wq + NW;
    u16* Wv = Wk + NW;
    u16* Wd = Wv + NW;
    u16* Qh = Wd + NW;
    u16* Kh = Qh + NT;
    u16* Vh = Kh + NT;
    u16* Obf = Vh + NT;
    u32* ctr = (u32*)(Obf + NT);

    hipMemsetAsync(ctr, 0, 4, stream);
    conv_all<<<dim3((unsigned)(NT / 1024), 7), blk, 0, stream>>>(
        q, k, v, wq_w, wk_w, wv_w, dw, Xq, Xk, Xv, Wq, Wk, Wv, Wd, NT, NW);
    gemm_qkv3<<<dim3(1536), blk, 0, stream>>>(
        Xq, Xk, Xv, Wq, Wk, Wv, wq_b, wk_b, wv_b, Qh, Kh, Vh);
    flash_attn<<<gattn, blk, 0, stream>>>(Qh, Kh, Vh, Obf, ctr);
    gemm_one<<<dim3(512), blk, 0, stream>>>(Obf, Wd, db, out, 1);
  } else {
    u16* Xbf = (u16*)d_ws;
    u16* Wbf = Xbf + NT;
    u16* Qh = Wbf + NW;
    u16* Kh = Qh + NT;
    u16* Vh = Kh + NT;
    u16* Obf = Vh + NT;
    u32* ctr = (u32*)(Obf + NT);
    const dim3 gact((unsigned)(NT / 1024));
    const dim3 gw((unsigned)(NW / 1024));

    hipMemsetAsync(ctr, 0, 4, stream);
    conv_f32_bf16<<<gact, blk, 0, stream>>>(q, Xbf);
    conv_f32_bf16<<<gw, blk, 0, stream>>>(wq_w, Wbf);
    gemm_one<<<dim3(512), blk, 0, stream>>>(Xbf, Wbf, wq_b, Qh, 0);
    conv_f32_bf16<<<gact, blk, 0, stream>>>(k, Xbf);
    conv_f32_bf16<<<gw, blk, 0, stream>>>(wk_w, Wbf);
    gemm_one<<<dim3(512), blk, 0, stream>>>(Xbf, Wbf, wk_b, Kh, 0);
    conv_f32_bf16<<<gact, blk, 0, stream>>>(v, Xbf);
    conv_f32_bf16<<<gw, blk, 0, stream>>>(wv_w, Wbf);
    gemm_one<<<dim3(512), blk, 0, stream>>>(Xbf, Wbf, wv_b, Vh, 0);
    flash_attn<<<gattn, blk, 0, stream>>>(Qh, Kh, Vh, Obf, ctr);
    conv_f32_bf16<<<gw, blk, 0, stream>>>(dw, Wbf);
    gemm_one<<<dim3(512), blk, 0, stream>>>(Obf, Wbf, db, out, 1);
  }
}

// Round 15
// 295.771 us; speedup vs baseline: 1.4827x; 1.4827x over previous
//
#include <hip/hip_runtime.h>
#include <hip/hip_bf16.h>

// GPT3 attention block, B=2 S=2048 D=2048 H=16 Dh=128.
// 4-phase/iter 128x128 counted-vmcnt GEMM (2 blocks/CU, L2/L3-aware XCD
// map) + K-split flash attention (swapped-QK^T 32x32, f32 partial merge).

typedef __bf16 bf16x8 __attribute__((ext_vector_type(8)));
typedef float f32x4 __attribute__((ext_vector_type(4)));
typedef float f32x16 __attribute__((ext_vector_type(16)));
typedef unsigned short u16;
typedef unsigned int u32;

#define DEV static __device__ __forceinline__

DEV void gload_lds16(const void* g, void* l) {
  __builtin_amdgcn_global_load_lds(
      (const __attribute__((address_space(1))) void*)g,
      (__attribute__((address_space(3))) void*)l, 16, 0, 0);
}

DEV f32x4 mfma16(bf16x8 a, bf16x8 b, f32x4 c) {
  return __builtin_amdgcn_mfma_f32_16x16x32_bf16(a, b, c, 0, 0, 0);
}

DEV f32x16 mfma32(bf16x8 a, bf16x8 b, f32x16 c) {
  return __builtin_amdgcn_mfma_f32_32x32x16_bf16(a, b, c, 0, 0, 0);
}

DEV u16 f2bf(float x) {
  return __builtin_bit_cast(u16, __float2bfloat16(x));
}

DEV u32 pack2(float lo, float hi_) {
  return (u32)f2bf(lo) | ((u32)f2bf(hi_) << 16);
}

#define BAR() __builtin_amdgcn_s_barrier()

// ---------------- fp32 -> bf16 conversion ----------------------------
__global__ void __launch_bounds__(256) conv_f32_bf16(
    const float* __restrict__ in, u16* __restrict__ out) {
  const size_t i = ((size_t)blockIdx.x * 256 + threadIdx.x) * 4;
  const float4 v = *reinterpret_cast<const float4*>(in + i);
  ushort4 o;
  o.x = f2bf(v.x); o.y = f2bf(v.y); o.z = f2bf(v.z); o.w = f2bf(v.w);
  *reinterpret_cast<ushort4*>(out + i) = o;
}

__global__ void __launch_bounds__(256) conv_all(
    const float* __restrict__ s0, const float* __restrict__ s1,
    const float* __restrict__ s2, const float* __restrict__ s3,
    const float* __restrict__ s4, const float* __restrict__ s5,
    const float* __restrict__ s6,
    u16* __restrict__ d0, u16* __restrict__ d1, u16* __restrict__ d2,
    u16* __restrict__ d3, u16* __restrict__ d4, u16* __restrict__ d5,
    u16* __restrict__ d6, const size_t nact, const size_t nw) {
  const int j = blockIdx.y;
  const size_t i = ((size_t)blockIdx.x * 256 + threadIdx.x) * 4;
  const float* s; u16* d; size_t n;
  switch (j) {
    case 0: s = s0; d = d0; n = nact; break;
    case 1: s = s1; d = d1; n = nact; break;
    case 2: s = s2; d = d2; n = nact; break;
    case 3: s = s3; d = d3; n = nw; break;
    case 4: s = s4; d = d4; n = nw; break;
    case 5: s = s5; d = d5; n = nw; break;
    default: s = s6; d = d6; n = nw; break;
  }
  if (i >= n) return;
  const float4 v = *reinterpret_cast<const float4*>(s + i);
  ushort4 o;
  o.x = f2bf(v.x); o.y = f2bf(v.y); o.z = f2bf(v.z); o.w = f2bf(v.w);
  *reinterpret_cast<ushort4*>(d + i) = o;
}

// ---------------- 4-phase 128x128 GEMM: C = A @ B^T + bias ------------
// (unchanged from r13: 16 MFMA/phase, counted vmcnt(4) at ph1/ph3,
// pair-row XOR swizzle, 2 blocks/CU)
#define GK 2048

DEV void gemm128_core(const u16* __restrict__ A, const u16* __restrict__ Bw,
                      const float* __restrict__ bias, void* __restrict__ Cout,
                      const int m0, const int n0, const int N,
                      const int out_f32, u16* AsB, u16* BsB) {
  const int tid = threadIdx.x;
  const int lane = tid & 63;
  const int wid = tid >> 6;
  const int wr = wid >> 1, wc = wid & 1;
  const int g = lane >> 4;
  const int r16 = lane & 15;

  int offA[2], offB[2], dstE[2];
#pragma unroll
  for (int rr = 0; rr < 2; ++rr) {
    const int G = rr * 256 + tid;
    const int rp = G >> 3;
    const int s = (G & 7) ^ (rp & 7);
    const int row = rp * 2 + (s >> 2);
    const int ch = s & 3;
    offA[rr] = (m0 + row) * GK + ch * 8;
    offB[rr] = (n0 + row) * GK + ch * 8;
    dstE[rr] = rr * 2048 + wid * 512;
  }

#define STAGE_A(kt, kh) do {                                              \
    u16* base_ = AsB + (((kt) & 1) * 2 + (kh)) * 4096;                    \
    const int go_ = (kt) * 64 + (kh) * 32;                                \
    gload_lds16(A + (size_t)(offA[0] + go_), base_ + dstE[0]);            \
    gload_lds16(A + (size_t)(offA[1] + go_), base_ + dstE[1]);            \
  } while (0)
#define STAGE_B(kt, kh) do {                                              \
    u16* base_ = BsB + (((kt) & 1) * 2 + (kh)) * 4096;                    \
    const int go_ = (kt) * 64 + (kh) * 32;                                \
    gload_lds16(Bw + (size_t)(offB[0] + go_), base_ + dstE[0]);           \
    gload_lds16(Bw + (size_t)(offB[1] + go_), base_ + dstE[1]);           \
  } while (0)
#define READ_A2(MH, buf) do {                                             \
    _Pragma("unroll") for (int i_ = 0; i_ < 2; ++i_) {                    \
      const int row_ = wr * 64 + ((MH) * 2 + i_) * 16 + r16;              \
      const int rp_ = row_ >> 1;                                          \
      const int sl_ = (((row_ & 1) << 2) | g) ^ (rp_ & 7);                \
      const int off_ = rp_ * 64 + sl_ * 8;                                \
      af[i_][0] = *(const bf16x8*)(AsB + ((buf) * 2 + 0) * 4096 + off_);  \
      af[i_][1] = *(const bf16x8*)(AsB + ((buf) * 2 + 1) * 4096 + off_);  \
    } } while (0)
#define READ_B4(buf) do {                                                 \
    _Pragma("unroll") for (int j_ = 0; j_ < 4; ++j_) {                    \
      const int row_ = wc * 64 + j_ * 16 + r16;                           \
      const int rp_ = row_ >> 1;                                          \
      const int sl_ = (((row_ & 1) << 2) | g) ^ (rp_ & 7);                \
      const int off_ = rp_ * 64 + sl_ * 8;                                \
      bf[j_][0] = *(const bf16x8*)(BsB + ((buf) * 2 + 0) * 4096 + off_);  \
      bf[j_][1] = *(const bf16x8*)(BsB + ((buf) * 2 + 1) * 4096 + off_);  \
    } } while (0)
#define MFMA16(MH) do {                                                   \
    __builtin_amdgcn_s_setprio(1);                                        \
    _Pragma("unroll") for (int i_ = 0; i_ < 2; ++i_)                      \
    _Pragma("unroll") for (int j_ = 0; j_ < 4; ++j_) {                    \
      f32x4 c_ = acc[(MH) * 2 + i_][j_];                                  \
      c_ = mfma16(af[i_][0], bf[j_][0], c_);                              \
      c_ = mfma16(af[i_][1], bf[j_][1], c_);                              \
      acc[(MH) * 2 + i_][j_] = c_;                                        \
    }                                                                     \
    __builtin_amdgcn_s_setprio(0);                                        \
  } while (0)

  f32x4 acc[4][4];
#pragma unroll
  for (int i = 0; i < 4; ++i)
#pragma unroll
    for (int j = 0; j < 4; ++j) acc[i][j] = {0.f, 0.f, 0.f, 0.f};

  bf16x8 af[2][2], bf[4][2];

  STAGE_B(0, 0); STAGE_B(0, 1); STAGE_A(0, 0); STAGE_A(0, 1);
  STAGE_B(1, 0); STAGE_B(1, 1);
  asm volatile("s_waitcnt vmcnt(4)" ::: "memory");
  BAR();

  for (int it = 0; it < 16; ++it) {
    const bool tail = (it == 15);
    const int T = 2 * it;
    const int b0 = T & 1, b1 = (T + 1) & 1;
    READ_A2(0, b0); READ_B4(b0);
    STAGE_A(T + 1, 0); STAGE_A(T + 1, 1);
    BAR(); MFMA16(0); BAR();
    READ_A2(1, b0);
    if (!tail) {
      STAGE_B(T + 2, 0); STAGE_B(T + 2, 1);
      asm volatile("s_waitcnt vmcnt(4)" ::: "memory");
    } else {
      asm volatile("s_waitcnt vmcnt(0)" ::: "memory");
    }
    BAR(); MFMA16(1); BAR();
    READ_A2(0, b1); READ_B4(b1);
    if (!tail) { STAGE_A(T + 2, 0); STAGE_A(T + 2, 1); }
    BAR(); MFMA16(0); BAR();
    READ_A2(1, b1);
    if (!tail) {
      STAGE_B(T + 3, 0); STAGE_B(T + 3, 1);
      asm volatile("s_waitcnt vmcnt(4)" ::: "memory");
    } else {
      asm volatile("s_waitcnt vmcnt(0)" ::: "memory");
    }
    BAR(); MFMA16(1); BAR();
  }

  const int rbase = m0 + wr * 64 + g * 4;
  const int cb = n0 + wc * 64 + r16;
#pragma unroll
  for (int i = 0; i < 4; ++i) {
#pragma unroll
    for (int j = 0; j < 4; ++j) {
      const int c = cb + j * 16;
      const float bv = bias[c];
#pragma unroll
      for (int r = 0; r < 4; ++r) {
        const float v = acc[i][j][r] + bv;
        const size_t idx = (size_t)(rbase + i * 16 + r) * N + c;
        if (out_f32) ((float*)Cout)[idx] = v;
        else ((u16*)Cout)[idx] = f2bf(v);
      }
    }
  }
#undef STAGE_A
#undef STAGE_B
#undef READ_A2
#undef READ_B4
#undef MFMA16
}

__global__ void __launch_bounds__(256, 2) gemm_qkv3(
    const u16* __restrict__ A0, const u16* __restrict__ A1,
    const u16* __restrict__ A2, const u16* __restrict__ W0,
    const u16* __restrict__ W1, const u16* __restrict__ W2,
    const float* __restrict__ b0, const float* __restrict__ b1,
    const float* __restrict__ b2, u16* __restrict__ C0,
    u16* __restrict__ C1, u16* __restrict__ C2) {
  __shared__ u16 AsB[4 * 4096];
  __shared__ u16 BsB[4 * 4096];
  const int xcd = blockIdx.x & 7;
  const int t = blockIdx.x >> 3;
  const int which = t >> 6;
  const int r = t & 63;
  const int m0 = (xcd * 4 + (r >> 4)) << 7;
  const int n0 = (r & 15) << 7;
  const u16* A = which == 0 ? A0 : which == 1 ? A1 : A2;
  const u16* W = which == 0 ? W0 : which == 1 ? W1 : W2;
  const float* bb = which == 0 ? b0 : which == 1 ? b1 : b2;
  u16* C = which == 0 ? C0 : which == 1 ? C1 : C2;
  gemm128_core(A, W, bb, C, m0, n0, 2048, 0, AsB, BsB);
}

__global__ void __launch_bounds__(256, 2) gemm_one(
    const u16* __restrict__ A, const u16* __restrict__ Bw,
    const float* __restrict__ bias, void* __restrict__ Cout,
    const int out_f32) {
  __shared__ u16 AsB[4 * 4096];
  __shared__ u16 BsB[4 * 4096];
  const int xcd = blockIdx.x & 7;
  const int t = blockIdx.x >> 3;
  const int m0 = (xcd * 4 + (t >> 4)) << 7;
  const int n0 = (t & 15) << 7;
  gemm128_core(A, Bw, bias, Cout, m0, n0, 2048, out_f32, AsB, BsB);
}

// ---------------- K-split causal flash attention ----------------------
// r15: longest job bounds any unsplit schedule's makespan (qt=15 => 32
// k-tiles). Split qt>=8 jobs into two independent K-halves, each block
// emitting unnormalized partials (O' f32, m, l) to scratch; merge kernel
// combines. 768 static jobs, sizes 2..17 tiles, 3 blocks/CU.
//   c in [0,512): split: qt=15-(c>>6) (desc), half=(c>>5)&1, bh=c&31,
//                 kt in [half*(qt+1), (half+1)*(qt+1))
//   c in [512,768): full: qt=(c-512)>>5 (asc), bh=c&31, kt in [0,2qt+2)
// Co-resident triples (c, c+256, c+512) sum ~= 30-36 tiles (banded).
// r14 lesson: NO __launch_bounds__ min-wave 3 (spilled oacc, WRITE 105MB).
#define SEQ 2048
#define DMODEL 2048
#define DH 128
#define QBLK 128
#define KBLK 64
#define PHALF 16640  // floats per partial half: 128*128 O' + 128 m + 128 l
#define C1 0.12751744f   // (1/sqrt(128)) * log2(e)
#define THR_RAW 62.73f   // defer-max threshold: 8 / C1

__global__ void __launch_bounds__(256, 2) flash_attn(
    const u16* __restrict__ Qh, const u16* __restrict__ Kh,
    const u16* __restrict__ Vh, u16* __restrict__ O,
    float* __restrict__ Pbuf) {
  __shared__ u16 Ks[2][KBLK * DH];  // 32 KB
  __shared__ u16 Vt[DH * KBLK];     // 16 KB

  const int tid = threadIdx.x;
  const int lane = tid & 63;
  const int w = tid >> 6;
  const int hi = lane >> 5;
  const int l31 = lane & 31;

  // static job decode
  const int c = blockIdx.x;
  int qt, bh, ktLo, ktHi, half;
  bool split;
  if (c < 512) {
    split = true;
    qt = 15 - (c >> 6);
    half = (c >> 5) & 1;
    bh = c & 31;
    const int L = qt + 1;
    ktLo = half * L;
    ktHi = ktLo + L;
  } else {
    split = false;
    half = 0;
    const int i = c - 512;
    qt = i >> 5;
    bh = i & 31;
    ktLo = 0;
    ktHi = 2 * qt + 2;
  }
  const int h = bh & 15;
  const int b = bh >> 4;
  const int q0 = qt * QBLK;
  const size_t rowbase = (size_t)b * SEQ;
  const int hoff = h * DH;
  const int qw = q0 + w * 32;
  const int qlane = qw + l31;

  bf16x8 aq[8];
  {
    const u16* qp = &Qh[(rowbase + qlane) * DMODEL + hoff + hi * 8];
#pragma unroll
    for (int cc = 0; cc < 8; ++cc)
      aq[cc] = *reinterpret_cast<const bf16x8*>(qp + cc * 16);
  }

  f32x16 oacc[4];
#pragma unroll
  for (int dt = 0; dt < 4; ++dt)
#pragma unroll
    for (int r = 0; r < 16; ++r) oacc[dt][r] = 0.f;
  float mrow = -1e30f, lrow = 0.f;

  const int krl = w * 16 + (lane >> 4);
  const int kg4 = w * 4 + (lane >> 4);
  const int du = lane & 15;

  const int ktd = qw >> 6;  // wave's diagonal tile (absolute)

  auto stageK = [&](int kt) {
#pragma unroll
    for (int i = 0; i < 4; ++i) {
      const int r = krl + i * 4;
      const int cg = (lane & 15) ^ (r & 15);
      gload_lds16(&Kh[(rowbase + kt * KBLK + r) * DMODEL + hoff + cg * 8],
                  &Ks[kt & 1][(w * 16 + i * 4) * DH]);
    }
  };

  stageK(ktLo);
  uint4 vv[4];
#pragma unroll
  for (int r = 0; r < 4; ++r)
    vv[r] = *reinterpret_cast<const uint4*>(
        &Vh[(rowbase + ktLo * KBLK + kg4 * 4 + r) * DMODEL + hoff + du * 8]);

  for (int kt = ktLo; kt < ktHi; ++kt) {
    const int k0 = kt * KBLK;
    if (kt + 1 < ktHi) {
      stageK(kt + 1);
      asm volatile("s_waitcnt vmcnt(4)" ::: "memory");
    } else {
      asm volatile("s_waitcnt vmcnt(0)" ::: "memory");
    }

#pragma unroll
    for (int j = 0; j < 8; ++j) {
      const int d = du * 8 + j;
      ushort4 pk4;
      pk4.x = ((const u16*)&vv[0])[j];
      pk4.y = ((const u16*)&vv[1])[j];
      pk4.z = ((const u16*)&vv[2])[j];
      pk4.w = ((const u16*)&vv[3])[j];
      const int slot = (((kg4 >> 1) ^ ((d >> 2) & 7)) * 8) + (kg4 & 1) * 4;
      *reinterpret_cast<ushort4*>(&Vt[d * KBLK + slot]) = pk4;
    }
    asm volatile("s_waitcnt lgkmcnt(0)" ::: "memory");
    BAR();

    const bool active = (kt <= ktd);
    const u16* kb = &Ks[kt & 1][0];
    float p[2][16];
    bool act1 = false;

    if (active) {
      const bool diag = (kt == ktd);
      act1 = (kt < ktd) || (w & 1);
      const bool m0q = diag && !(w & 1);
      const bool m1q = diag && (w & 1);
      {
        f32x16 s;
#pragma unroll
        for (int r = 0; r < 16; ++r) s[r] = 0.f;
        __builtin_amdgcn_s_setprio(1);
#pragma unroll
        for (int cc = 0; cc < 8; ++cc) {
          const int row = l31;
          const bf16x8 kf = *reinterpret_cast<const bf16x8*>(
              &kb[row * DH + (((cc * 2 + hi) ^ (row & 15)) * 8)]);
          s = mfma32(kf, aq[cc], s);
        }
        __builtin_amdgcn_s_setprio(0);
#pragma unroll
        for (int r = 0; r < 16; ++r) {
          const int krow = (r & 3) + 8 * (r >> 2) + 4 * hi;
          p[0][r] = (m0q && (k0 + krow > qlane)) ? -1e9f : s[r];
        }
      }
      if (act1) {
        f32x16 s;
#pragma unroll
        for (int r = 0; r < 16; ++r) s[r] = 0.f;
        __builtin_amdgcn_s_setprio(1);
#pragma unroll
        for (int cc = 0; cc < 8; ++cc) {
          const int row = 32 + l31;
          const bf16x8 kf = *reinterpret_cast<const bf16x8*>(
              &kb[row * DH + (((cc * 2 + hi) ^ (row & 15)) * 8)]);
          s = mfma32(kf, aq[cc], s);
        }
        __builtin_amdgcn_s_setprio(0);
#pragma unroll
        for (int r = 0; r < 16; ++r) {
          const int krow = (r & 3) + 8 * (r >> 2) + 4 * hi;
          p[1][r] = (m1q && (k0 + 32 + krow > qlane)) ? -1e9f : s[r];
        }
      } else {
#pragma unroll
        for (int r = 0; r < 16; ++r) p[1][r] = -1e9f;
      }
    }

    if (kt + 1 < ktHi) {
#pragma unroll
      for (int r = 0; r < 4; ++r)
        vv[r] = *reinterpret_cast<const uint4*>(
            &Vh[(rowbase + k0 + KBLK + kg4 * 4 + r) * DMODEL + hoff +
                du * 8]);
    }

    if (active) {
      float mx0 = fmaxf(p[0][0], p[1][0]);
      float mx1 = fmaxf(p[0][1], p[1][1]);
      float mx2 = fmaxf(p[0][2], p[1][2]);
      float mx3 = fmaxf(p[0][3], p[1][3]);
#pragma unroll
      for (int r = 4; r < 16; r += 4) {
        mx0 = fmaxf(mx0, fmaxf(p[0][r + 0], p[1][r + 0]));
        mx1 = fmaxf(mx1, fmaxf(p[0][r + 1], p[1][r + 1]));
        mx2 = fmaxf(mx2, fmaxf(p[0][r + 2], p[1][r + 2]));
        mx3 = fmaxf(mx3, fmaxf(p[0][r + 3], p[1][r + 3]));
      }
      float mx = fmaxf(fmaxf(mx0, mx1), fmaxf(mx2, mx3));
      mx = fmaxf(mx, __shfl_xor(mx, 32));

      const bool need = (mx > mrow + THR_RAW);
      if (__any((int)need)) {
        const float mn = fmaxf(mrow, mx);
        const float al = exp2f((mrow - mn) * C1);
        mrow = mn;
        lrow *= al;
#pragma unroll
        for (int r = 0; r < 16; ++r) {
          const float ar = __shfl(al, (r & 3) + 8 * (r >> 2) + 4 * hi);
#pragma unroll
          for (int dt = 0; dt < 4; ++dt) oacc[dt][r] *= ar;
        }
      }

      float s0 = 0.f, s1 = 0.f, s2 = 0.f, s3 = 0.f;
#pragma unroll
      for (int t = 0; t < 2; ++t)
#pragma unroll
        for (int r = 0; r < 16; r += 4) {
          p[t][r + 0] = exp2f((p[t][r + 0] - mrow) * C1);
          p[t][r + 1] = exp2f((p[t][r + 1] - mrow) * C1);
          p[t][r + 2] = exp2f((p[t][r + 2] - mrow) * C1);
          p[t][r + 3] = exp2f((p[t][r + 3] - mrow) * C1);
          s0 += p[t][r + 0]; s1 += p[t][r + 1];
          s2 += p[t][r + 2]; s3 += p[t][r + 3];
        }
      float sum = (s0 + s1) + (s2 + s3);
      sum += __shfl_xor(sum, 32);
      lrow += sum;

      u32 pk[2][8];
#pragma unroll
      for (int t = 0; t < 2; ++t)
#pragma unroll
        for (int m = 0; m < 8; ++m)
          pk[t][m] = pack2(p[t][2 * m], p[t][2 * m + 1]);

      __builtin_amdgcn_s_setprio(1);
#pragma unroll
      for (int ks = 0; ks < 4; ++ks) {
        if (ks >= 2 && !act1) break;
        const int t = ks >> 1;
        const int bs = (ks & 1) * 4;
        const u32 q0s = __shfl_xor(pk[t][bs + 0], 32);
        const u32 q1s = __shfl_xor(pk[t][bs + 1], 32);
        const u32 q2s = __shfl_xor(pk[t][bs + 2], 32);
        const u32 q3s = __shfl_xor(pk[t][bs + 3], 32);
        union { u32 u[4]; bf16x8 v; } pa;
        pa.u[0] = hi ? q2s : pk[t][bs + 0];
        pa.u[1] = hi ? q3s : pk[t][bs + 1];
        pa.u[2] = hi ? pk[t][bs + 2] : q0s;
        pa.u[3] = hi ? pk[t][bs + 3] : q1s;
#pragma unroll
        for (int dt = 0; dt < 4; ++dt) {
          const int d = dt * 32 + l31;
          const bf16x8 vf = *reinterpret_cast<const bf16x8*>(
              &Vt[d * KBLK + (((ks * 2 + hi) ^ ((d >> 2) & 7)) * 8)]);
          oacc[dt] = mfma32(pa.v, vf, oacc[dt]);
        }
      }
      __builtin_amdgcn_s_setprio(0);
    }

    BAR();
  }

  if (!split) {
    const float li = __builtin_amdgcn_rcpf(lrow);
#pragma unroll
    for (int r = 0; r < 16; ++r) {
      const int rowq = (r & 3) + 8 * (r >> 2) + 4 * hi;
      const float lr = __shfl(li, rowq);
      u16* op = &O[(rowbase + qw + rowq) * DMODEL + hoff + l31];
#pragma unroll
      for (int dt = 0; dt < 4; ++dt) op[dt * 32] = f2bf(oacc[dt][r] * lr);
    }
  } else {
    float* Pb = Pbuf + ((size_t)((((qt - 8) << 5) | bh) * 2 + half)) * PHALF;
#pragma unroll
    for (int r = 0; r < 16; ++r) {
      const int rowq = (r & 3) + 8 * (r >> 2) + 4 * hi;
      float* op = &Pb[(size_t)(w * 32 + rowq) * 128 + l31];
#pragma unroll
      for (int dt = 0; dt < 4; ++dt) op[dt * 32] = oacc[dt][r];
    }
    if (hi == 0) {
      Pb[16384 + w * 32 + l31] = mrow;
      Pb[16512 + w * 32 + l31] = lrow;
    }
  }
}

// merge the 256 split pairs: O = (a0*O0' + a1*O1') / (a0*l0 + a1*l1)
__global__ void __launch_bounds__(256) merge_split(
    const float* __restrict__ Pbuf, u16* __restrict__ O) {
  const int p = blockIdx.x;
  const int qt = 8 + (p >> 5);
  const int bh = p & 31;
  const int h = bh & 15;
  const int b = bh >> 4;
  const float* P0 = Pbuf + (size_t)(p * 2 + 0) * PHALF;
  const float* P1 = Pbuf + (size_t)(p * 2 + 1) * PHALF;
  const int row = threadIdx.x >> 1;
  const int d0 = (threadIdx.x & 1) * 64;
  const float m0 = P0[16384 + row], m1 = P1[16384 + row];
  const float l0 = P0[16512 + row], l1 = P1[16512 + row];
  const float m = fmaxf(m0, m1);
  const float a0 = exp2f((m0 - m) * C1);
  const float a1 = exp2f((m1 - m) * C1);
  const float li = 1.0f / (a0 * l0 + a1 * l1);
  u16* orow = &O[((size_t)b * SEQ + qt * QBLK + row) * DMODEL + h * DH + d0];
  const float* r0 = &P0[(size_t)row * 128 + d0];
  const float* r1 = &P1[(size_t)row * 128 + d0];
#pragma unroll
  for (int d = 0; d < 64; d += 4) {
    const f32x4 o0 = *reinterpret_cast<const f32x4*>(r0 + d);
    const f32x4 o1 = *reinterpret_cast<const f32x4*>(r1 + d);
    ushort4 s;
    s.x = f2bf((a0 * o0[0] + a1 * o1[0]) * li);
    s.y = f2bf((a0 * o0[1] + a1 * o1[1]) * li);
    s.z = f2bf((a0 * o0[2] + a1 * o1[2]) * li);
    s.w = f2bf((a0 * o0[3] + a1 * o1[3]) * li);
    *reinterpret_cast<ushort4*>(orow + d) = s;
  }
}

// ---------------- launcher --------------------------------------------
extern "C" void kernel_launch(void* const* d_in, const int* in_sizes, int n_in,
                              void* d_out, int out_size, void* d_ws,
                              size_t ws_size, hipStream_t stream) {
  const int Bv = 2, S = 2048, D = 2048;
  const int M = Bv * S;
  const size_t NT = (size_t)M * D;   // 8388608
  const size_t NW = (size_t)D * D;   // 4194304

  const float* q = (const float*)d_in[0];
  const float* k = (const float*)d_in[1];
  const float* v = (const float*)d_in[2];
  const float* wq_w = (const float*)d_in[4];
  const float* wq_b = (const float*)d_in[5];
  const float* wk_w = (const float*)d_in[6];
  const float* wk_b = (const float*)d_in[7];
  const float* wv_w = (const float*)d_in[8];
  const float* wv_b = (const float*)d_in[9];
  const float* dw = (const float*)d_in[10];
  const float* db = (const float*)d_in[11];
  float* out = (float*)d_out;

  const dim3 blk(256);
  const dim3 gattn(768);
  const size_t need = (7 * NT + 4 * NW) * 2;  // ~151 MB

  if (ws_size >= need) {
    u16* base = (u16*)d_ws;
    u16* Xq = base;
    u16* Xk = Xq + NT;
    u16* Xv = Xk + NT;
    u16* Wq = Xv + NT;
    u16* Wk = Wq + NW;
    u16* Wv = Wk + NW;
    u16* Wd = Wv + NW;
    u16* Qh = Wd + NW;
    u16* Kh = Qh + NT;
    u16* Vh = Kh + NT;
    u16* Obf = Vh + NT;
    // partials overlay the DEAD Xq/Xk/Xv region (dead after gemm_qkv3):
    // 512 halves x 16640 f32 = 34.1 MB < 48 MB
    float* Pbuf = (float*)Xq;

    conv_all<<<dim3((unsigned)(NT / 1024), 7), blk, 0, stream>>>(
        q, k, v, wq_w, wk_w, wv_w, dw, Xq, Xk, Xv, Wq, Wk, Wv, Wd, NT, NW);
    gemm_qkv3<<<dim3(1536), blk, 0, stream>>>(
        Xq, Xk, Xv, Wq, Wk, Wv, wq_b, wk_b, wv_b, Qh, Kh, Vh);
    flash_attn<<<gattn, blk, 0, stream>>>(Qh, Kh, Vh, Obf, Pbuf);
    merge_split<<<dim3(256), blk, 0, stream>>>(Pbuf, Obf);
    gemm_one<<<dim3(512), blk, 0, stream>>>(Obf, Wd, db, out, 1);
  } else {
    u16* Xbf = (u16*)d_ws;
    u16* Wbf = Xbf + NT;
    u16* Qh = Wbf + NW;
    u16* Kh = Qh + NT;
    u16* Vh = Kh + NT;
    u16* Obf = Vh + NT;
    float* Pbuf = (float*)(Obf + NT);
    const dim3 gact((unsigned)(NT / 1024));
    const dim3 gw((unsigned)(NW / 1024));

    conv_f32_bf16<<<gact, blk, 0, stream>>>(q, Xbf);
    conv_f32_bf16<<<gw, blk, 0, stream>>>(wq_w, Wbf);
    gemm_one<<<dim3(512), blk, 0, stream>>>(Xbf, Wbf, wq_b, Qh, 0);
    conv_f32_bf16<<<gact, blk, 0, stream>>>(k, Xbf);
    conv_f32_bf16<<<gw, blk, 0, stream>>>(wk_w, Wbf);
    gemm_one<<<dim3(512), blk, 0, stream>>>(Xbf, Wbf, wk_b, Kh, 0);
    conv_f32_bf16<<<gact, blk, 0, stream>>>(v, Xbf);
    conv_f32_bf16<<<gw, blk, 0, stream>>>(wv_w, Wbf);
    gemm_one<<<dim3(512), blk, 0, stream>>>(Xbf, Wbf, wv_b, Vh, 0);
    flash_attn<<<gattn, blk, 0, stream>>>(Qh, Kh, Vh, Obf, Pbuf);
    merge_split<<<dim3(256), blk, 0, stream>>>(Pbuf, Obf);
    conv_f32_bf16<<<gw, blk, 0, stream>>>(dw, Wbf);
    gemm_one<<<dim3(512), blk, 0, stream>>>(Obf, Wbf, db, out, 1);
  }
}